// Round 1
// baseline (372.795 us; speedup 1.0000x reference)
//
#include <hip/hip_runtime.h>
#include <hip/hip_bf16.h>

#define HIDDEN 4096
#define INTER 11008
#define MTOK 128  // 4*32 tokens

typedef float f32x4 __attribute__((ext_vector_type(4)));
typedef short s16x8 __attribute__((ext_vector_type(8)));

// fp32 -> bf16 round-to-nearest-even (bit trick)
__device__ __forceinline__ unsigned short f2bf(float f) {
    unsigned int u = __float_as_uint(f);
    u += 0x7FFFu + ((u >> 16) & 1u);
    return (unsigned short)(u >> 16);
}

__device__ __forceinline__ s16x8 cvt8(f32x4 a, f32x4 b) {
    s16x8 r;
    r[0] = (short)f2bf(a[0]); r[1] = (short)f2bf(a[1]);
    r[2] = (short)f2bf(a[2]); r[3] = (short)f2bf(a[3]);
    r[4] = (short)f2bf(b[0]); r[5] = (short)f2bf(b[1]);
    r[6] = (short)f2bf(b[2]); r[7] = (short)f2bf(b[3]);
    return r;
}

// ---------------- kernel 1: x fp32 -> bf16 ----------------
__global__ __launch_bounds__(256) void k_convert_x(const float* __restrict__ x,
                                                   unsigned short* __restrict__ xb) {
    int i = (blockIdx.x * 256 + threadIdx.x) * 4;
    f32x4 v = *reinterpret_cast<const f32x4*>(x + i);
    ushort4 o;
    o.x = f2bf(v[0]); o.y = f2bf(v[1]); o.z = f2bf(v[2]); o.w = f2bf(v[3]);
    *reinterpret_cast<ushort4*>(xb + i) = o;
}

// ---------------- kernel 2: gate & up GEMM + silu*up -> hb (bf16) ----------------
// grid.x = INTER/32 = 344 ; block = 256 (4 waves)
// waves 0,1: gate cols [n0, n0+16), [n0+16, n0+32) ; waves 2,3: same for up.
__global__ __launch_bounds__(256) void k_gateup(const unsigned short* __restrict__ xb,
                                                const float* __restrict__ wg,
                                                const float* __restrict__ wu,
                                                unsigned short* __restrict__ hb) {
    __shared__ __align__(16) unsigned short xs[MTOK * 72];  // 64 k + 8 pad per row
    const int tid = threadIdx.x;
    const int wave = tid >> 6, lane = tid & 63;
    const int r16 = lane & 15, g4 = lane >> 4;
    const int n0 = blockIdx.x * 32;

    const float* w = (wave < 2) ? wg : wu;
    const int wrow = n0 + (wave & 1) * 16 + r16;
    const float* wp = w + (size_t)wrow * HIDDEN + g4 * 8;

    f32x4 acc[8];
#pragma unroll
    for (int i = 0; i < 8; ++i) acc[i] = (f32x4)0.0f;

    for (int k0 = 0; k0 < HIDDEN; k0 += 64) {
        __syncthreads();
#pragma unroll
        for (int c = tid; c < 1024; c += 256) {
            int row = c >> 3, off = c & 7;
            *reinterpret_cast<uint4*>(&xs[row * 72 + off * 8]) =
                *reinterpret_cast<const uint4*>(xb + (size_t)row * HIDDEN + k0 + off * 8);
        }
        __syncthreads();
#pragma unroll
        for (int kk = 0; kk < 64; kk += 32) {
            f32x4 b0 = *reinterpret_cast<const f32x4*>(wp + k0 + kk);
            f32x4 b1 = *reinterpret_cast<const f32x4*>(wp + k0 + kk + 4);
            s16x8 bf = cvt8(b0, b1);
#pragma unroll
            for (int mt = 0; mt < 8; ++mt) {
                s16x8 af = *reinterpret_cast<const s16x8*>(&xs[(mt * 16 + r16) * 72 + kk + g4 * 8]);
                acc[mt] = __builtin_amdgcn_mfma_f32_16x16x32_bf16(af, bf, acc[mt], 0, 0, 0);
            }
        }
    }

    // epilogue: waves 2,3 (up) publish via LDS; waves 0,1 (gate) combine
    __syncthreads();
    float* ulds = reinterpret_cast<float*>(xs);  // [128][33] fp32, 16896 B < 18432 B
    if (wave >= 2) {
#pragma unroll
        for (int mt = 0; mt < 8; ++mt)
#pragma unroll
            for (int r = 0; r < 4; ++r) {
                int m = mt * 16 + g4 * 4 + r;
                ulds[m * 33 + (wave & 1) * 16 + r16] = acc[mt][r];
            }
    }
    __syncthreads();
    if (wave < 2) {
#pragma unroll
        for (int mt = 0; mt < 8; ++mt)
#pragma unroll
            for (int r = 0; r < 4; ++r) {
                int m = mt * 16 + g4 * 4 + r;
                int cl = (wave & 1) * 16 + r16;
                float gv = acc[mt][r];
                float uv = ulds[m * 33 + cl];
                float hv = gv / (1.0f + __expf(-gv)) * uv;
                hb[(size_t)m * INTER + n0 + cl] = f2bf(hv);
            }
    }
}

// ---------------- kernel 3: down GEMM (split-K x4) -> partials fp32 ----------------
// grid = (HIDDEN/64, 4) ; block = 256 (4 waves). wave w: cols n0+16w..+15
__global__ __launch_bounds__(256) void k_down(const unsigned short* __restrict__ hb,
                                              const float* __restrict__ wd,
                                              float* __restrict__ parts) {
    __shared__ __align__(16) unsigned short xs[MTOK * 72];
    const int tid = threadIdx.x;
    const int wave = tid >> 6, lane = tid & 63;
    const int r16 = lane & 15, g4 = lane >> 4;
    const int n0 = blockIdx.x * 64;
    const int kc = blockIdx.y;
    const int kbeg = kc * (INTER / 4);

    const int wrow = n0 + wave * 16 + r16;
    const float* wp = wd + (size_t)wrow * INTER + g4 * 8;

    f32x4 acc[8];
#pragma unroll
    for (int i = 0; i < 8; ++i) acc[i] = (f32x4)0.0f;

    for (int k0 = kbeg; k0 < kbeg + INTER / 4; k0 += 64) {
        __syncthreads();
#pragma unroll
        for (int c = tid; c < 1024; c += 256) {
            int row = c >> 3, off = c & 7;
            *reinterpret_cast<uint4*>(&xs[row * 72 + off * 8]) =
                *reinterpret_cast<const uint4*>(hb + (size_t)row * INTER + k0 + off * 8);
        }
        __syncthreads();
#pragma unroll
        for (int kk = 0; kk < 64; kk += 32) {
            f32x4 b0 = *reinterpret_cast<const f32x4*>(wp + k0 + kk);
            f32x4 b1 = *reinterpret_cast<const f32x4*>(wp + k0 + kk + 4);
            s16x8 bf = cvt8(b0, b1);
#pragma unroll
            for (int mt = 0; mt < 8; ++mt) {
                s16x8 af = *reinterpret_cast<const s16x8*>(&xs[(mt * 16 + r16) * 72 + kk + g4 * 8]);
                acc[mt] = __builtin_amdgcn_mfma_f32_16x16x32_bf16(af, bf, acc[mt], 0, 0, 0);
            }
        }
    }

    float* p = parts + (size_t)kc * (MTOK * HIDDEN);
#pragma unroll
    for (int mt = 0; mt < 8; ++mt)
#pragma unroll
        for (int r = 0; r < 4; ++r) {
            int m = mt * 16 + g4 * 4 + r;
            p[(size_t)m * HIDDEN + n0 + wave * 16 + r16] = acc[mt][r];
        }
}

// ---------------- kernel 4: reduce 4 partials -> out ----------------
__global__ __launch_bounds__(256) void k_reduce(const float* __restrict__ parts,
                                                float* __restrict__ out) {
    int i = (blockIdx.x * 256 + threadIdx.x) * 4;
    const int NT = MTOK * HIDDEN;
    f32x4 s = *reinterpret_cast<const f32x4*>(parts + i) +
              *reinterpret_cast<const f32x4*>(parts + NT + i) +
              *reinterpret_cast<const f32x4*>(parts + 2 * NT + i) +
              *reinterpret_cast<const f32x4*>(parts + 3 * NT + i);
    *reinterpret_cast<f32x4*>(out + i) = s;
}

extern "C" void kernel_launch(void* const* d_in, const int* in_sizes, int n_in,
                              void* d_out, int out_size, void* d_ws, size_t ws_size,
                              hipStream_t stream) {
    const float* x  = (const float*)d_in[0];
    const float* wg = (const float*)d_in[1];
    const float* wu = (const float*)d_in[2];
    const float* wd = (const float*)d_in[3];
    float* out = (float*)d_out;

    char* ws = (char*)d_ws;
    unsigned short* xb = (unsigned short*)ws;                      // 1,048,576 B
    unsigned short* hb = (unsigned short*)(ws + 1048576);          // 2,818,048 B
    float* parts = (float*)(ws + 1048576 + 2818048);               // 8,388,608 B

    k_convert_x<<<512, 256, 0, stream>>>(x, xb);
    k_gateup<<<INTER / 32, 256, 0, stream>>>(xb, wg, wu, hb);
    k_down<<<dim3(HIDDEN / 64, 4), 256, 0, stream>>>(hb, wd, parts);
    k_reduce<<<512, 256, 0, stream>>>(parts, out);
}

// Round 2
// 363.847 us; speedup vs baseline: 1.0246x; 1.0246x over previous
//
#include <hip/hip_runtime.h>
#include <hip/hip_bf16.h>

#define HIDDEN 4096
#define INTER 11008
#define MTOK 128  // 4*32 tokens

typedef float f32x4 __attribute__((ext_vector_type(4)));
typedef short s16x8 __attribute__((ext_vector_type(8)));

__device__ __forceinline__ unsigned short f2bf(float f) {
    unsigned int u = __float_as_uint(f);
    u += 0x7FFFu + ((u >> 16) & 1u);
    return (unsigned short)(u >> 16);
}

__device__ __forceinline__ s16x8 cvt8(f32x4 a, f32x4 b) {
    s16x8 r;
    r[0] = (short)f2bf(a[0]); r[1] = (short)f2bf(a[1]);
    r[2] = (short)f2bf(a[2]); r[3] = (short)f2bf(a[3]);
    r[4] = (short)f2bf(b[0]); r[5] = (short)f2bf(b[1]);
    r[6] = (short)f2bf(b[2]); r[7] = (short)f2bf(b[3]);
    return r;
}

// ---------------- kernel 1: x fp32 -> bf16 ----------------
__global__ __launch_bounds__(256) void k_convert_x(const float* __restrict__ x,
                                                   unsigned short* __restrict__ xb) {
    int i = (blockIdx.x * 256 + threadIdx.x) * 4;
    f32x4 v = *reinterpret_cast<const f32x4*>(x + i);
    ushort4 o;
    o.x = f2bf(v[0]); o.y = f2bf(v[1]); o.z = f2bf(v[2]); o.w = f2bf(v[3]);
    *reinterpret_cast<ushort4*>(xb + i) = o;
}

// ---------------- kernel 2: gate & up GEMM, barrier-free, split-K ----------------
// Each WAVE independently owns (mat, 16-col n-tile, K-chunk). A-frags read from
// L2-resident xb; weights streamed fp32->bf16. grid.x = 344*Sg blocks (4 waves each).
__global__ __launch_bounds__(256, 4) void k_gateup2(const unsigned short* __restrict__ xb,
                                                    const float* __restrict__ wg,
                                                    const float* __restrict__ wu,
                                                    float* __restrict__ pg,
                                                    float* __restrict__ pu, int Sg) {
    const int tid = threadIdx.x;
    const int wave = tid >> 6, lane = tid & 63;
    const int r16 = lane & 15, g4 = lane >> 4;

    int gid = blockIdx.x * 4 + wave;           // [0, 688*2*Sg)
    int nt = gid % 688;                        // n-tile (adjacent waves -> adjacent tiles)
    int rest = gid / 688;                      // [0, 2*Sg)
    int mat = rest & 1;                        // 0 = gate, 1 = up
    int kc = rest >> 1;                        // [0, Sg)
    int n0 = nt * 16;

    const float* w = mat ? wu : wg;
    const float* wp = w + (size_t)(n0 + r16) * HIDDEN + g4 * 8;
    const unsigned short* xa = xb + (size_t)r16 * HIDDEN + g4 * 8;

    const int nk = (HIDDEN / 32) / Sg;         // k-steps (32 K each) in this chunk
    const int kbeg = kc * nk * 32;

    f32x4 acc[8];
#pragma unroll
    for (int i = 0; i < 8; ++i) acc[i] = (f32x4)0.0f;

#pragma unroll 2
    for (int s = 0; s < nk; ++s) {
        int k = kbeg + s * 32;
        f32x4 b0 = *reinterpret_cast<const f32x4*>(wp + k);
        f32x4 b1 = *reinterpret_cast<const f32x4*>(wp + k + 4);
        s16x8 bf = cvt8(b0, b1);
#pragma unroll
        for (int mt = 0; mt < 8; ++mt) {
            s16x8 af = *reinterpret_cast<const s16x8*>(xa + (size_t)mt * 16 * HIDDEN + k);
            acc[mt] = __builtin_amdgcn_mfma_f32_16x16x32_bf16(af, bf, acc[mt], 0, 0, 0);
        }
    }

    float* p = (mat ? pu : pg) + (size_t)kc * (MTOK * INTER);
#pragma unroll
    for (int mt = 0; mt < 8; ++mt)
#pragma unroll
        for (int r = 0; r < 4; ++r) {
            int m = mt * 16 + g4 * 4 + r;
            p[(size_t)m * INTER + n0 + r16] = acc[mt][r];
        }
}

// ---------------- kernel 3: combine partials + silu*up -> hb bf16 ----------------
// grid = 1376 blocks x 256 thr, 4 elems/thread (128*11008 total)
__global__ __launch_bounds__(256) void k_combine(const float* __restrict__ pg,
                                                 const float* __restrict__ pu,
                                                 unsigned short* __restrict__ hb, int Sg) {
    size_t i = (size_t)(blockIdx.x * 256 + threadIdx.x) * 4;
    f32x4 g = (f32x4)0.0f, u = (f32x4)0.0f;
    for (int c = 0; c < Sg; ++c) {
        g += *reinterpret_cast<const f32x4*>(pg + (size_t)c * (MTOK * INTER) + i);
        u += *reinterpret_cast<const f32x4*>(pu + (size_t)c * (MTOK * INTER) + i);
    }
    ushort4 o;
    float h0 = g[0] / (1.0f + __expf(-g[0])) * u[0];
    float h1 = g[1] / (1.0f + __expf(-g[1])) * u[1];
    float h2 = g[2] / (1.0f + __expf(-g[2])) * u[2];
    float h3 = g[3] / (1.0f + __expf(-g[3])) * u[3];
    o.x = f2bf(h0); o.y = f2bf(h1); o.z = f2bf(h2); o.w = f2bf(h3);
    *reinterpret_cast<ushort4*>(hb + i) = o;
}

// ---------------- kernel 4: down GEMM, barrier-free, split-K ----------------
// grid.x = 64*Sd blocks (4 waves). Wave owns (16-col n-tile, K-chunk).
__global__ __launch_bounds__(256, 4) void k_down2(const unsigned short* __restrict__ hb,
                                                  const float* __restrict__ wd,
                                                  float* __restrict__ pd, int Sd) {
    const int tid = threadIdx.x;
    const int wave = tid >> 6, lane = tid & 63;
    const int r16 = lane & 15, g4 = lane >> 4;

    int gid = blockIdx.x * 4 + wave;           // [0, 256*Sd)
    int nt = gid % 256;
    int kc = gid / 256;                        // [0, Sd)
    int n0 = nt * 16;

    const float* wp = wd + (size_t)(n0 + r16) * INTER + g4 * 8;
    const unsigned short* xa = hb + (size_t)r16 * INTER + g4 * 8;

    const int sbeg = (344 * kc) / Sd;          // k-steps of 32; 344 total
    const int send = (344 * (kc + 1)) / Sd;

    f32x4 acc[8];
#pragma unroll
    for (int i = 0; i < 8; ++i) acc[i] = (f32x4)0.0f;

#pragma unroll 2
    for (int s = sbeg; s < send; ++s) {
        int k = s * 32;
        f32x4 b0 = *reinterpret_cast<const f32x4*>(wp + k);
        f32x4 b1 = *reinterpret_cast<const f32x4*>(wp + k + 4);
        s16x8 bf = cvt8(b0, b1);
#pragma unroll
        for (int mt = 0; mt < 8; ++mt) {
            s16x8 af = *reinterpret_cast<const s16x8*>(xa + (size_t)mt * 16 * INTER + k);
            acc[mt] = __builtin_amdgcn_mfma_f32_16x16x32_bf16(af, bf, acc[mt], 0, 0, 0);
        }
    }

    float* p = pd + (size_t)kc * (MTOK * HIDDEN);
#pragma unroll
    for (int mt = 0; mt < 8; ++mt)
#pragma unroll
        for (int r = 0; r < 4; ++r) {
            int m = mt * 16 + g4 * 4 + r;
            p[(size_t)m * HIDDEN + n0 + r16] = acc[mt][r];
        }
}

// ---------------- kernel 5: reduce Sd partials -> out ----------------
__global__ __launch_bounds__(256) void k_reduce(const float* __restrict__ pd,
                                                float* __restrict__ out, int Sd) {
    int i = (blockIdx.x * 256 + threadIdx.x) * 4;
    const int NT = MTOK * HIDDEN;
    f32x4 s = (f32x4)0.0f;
    for (int c = 0; c < Sd; ++c)
        s += *reinterpret_cast<const f32x4*>(pd + (size_t)c * NT + i);
    *reinterpret_cast<f32x4*>(out + i) = s;
}

extern "C" void kernel_launch(void* const* d_in, const int* in_sizes, int n_in,
                              void* d_out, int out_size, void* d_ws, size_t ws_size,
                              hipStream_t stream) {
    const float* x  = (const float*)d_in[0];
    const float* wg = (const float*)d_in[1];
    const float* wu = (const float*)d_in[2];
    const float* wd = (const float*)d_in[3];
    float* out = (float*)d_out;

    // Pick largest split factors that fit ws_size.
    const size_t XB = 1048576;               // x bf16
    const size_t HB = 2818048;               // h bf16
    const size_t PGU = (size_t)MTOK * INTER * 4;   // 5,636,096 per split per matrix
    const size_t PD  = (size_t)MTOK * HIDDEN * 4;  // 2,097,152 per split
    const int cfg[5][2] = {{4, 16}, {4, 8}, {2, 8}, {2, 4}, {1, 2}};
    int Sg = 1, Sd = 2;
    for (int c = 0; c < 5; ++c) {
        size_t need = XB + HB + 2 * (size_t)cfg[c][0] * PGU + (size_t)cfg[c][1] * PD;
        if (need <= ws_size) { Sg = cfg[c][0]; Sd = cfg[c][1]; break; }
    }

    char* ws = (char*)d_ws;
    unsigned short* xb = (unsigned short*)ws;
    unsigned short* hb = (unsigned short*)(ws + XB);
    float* pg = (float*)(ws + XB + HB);
    float* pu = pg + (size_t)Sg * (MTOK * INTER);
    float* pd = pu + (size_t)Sg * (MTOK * INTER);

    k_convert_x<<<512, 256, 0, stream>>>(x, xb);
    k_gateup2<<<344 * Sg, 256, 0, stream>>>(xb, wg, wu, pg, pu, Sg);
    k_combine<<<1376, 256, 0, stream>>>(pg, pu, hb, Sg);
    k_down2<<<64 * Sd, 256, 0, stream>>>(hb, wd, pd, Sd);
    k_reduce<<<512, 256, 0, stream>>>(pd, out, Sd);
}

// Round 3
// 167.376 us; speedup vs baseline: 2.2273x; 2.1738x over previous
//
#include <hip/hip_runtime.h>
#include <hip/hip_bf16.h>

#define HIDDEN 4096
#define INTER 11008
#define MTOK 128  // 4*32 tokens

typedef float f32x4 __attribute__((ext_vector_type(4)));
typedef short s16x8 __attribute__((ext_vector_type(8)));
typedef __attribute__((address_space(3))) unsigned int as3_u32;
typedef __attribute__((address_space(1))) unsigned int as1_u32;

__device__ __forceinline__ unsigned short f2bf(float f) {
    unsigned int u = __float_as_uint(f);
    u += 0x7FFFu + ((u >> 16) & 1u);
    return (unsigned short)(u >> 16);
}

__device__ __forceinline__ s16x8 cvt8(f32x4 a, f32x4 b) {
    s16x8 r;
    r[0] = (short)f2bf(a[0]); r[1] = (short)f2bf(a[1]);
    r[2] = (short)f2bf(a[2]); r[3] = (short)f2bf(a[3]);
    r[4] = (short)f2bf(b[0]); r[5] = (short)f2bf(b[1]);
    r[6] = (short)f2bf(b[2]); r[7] = (short)f2bf(b[3]);
    return r;
}

// ---------------- kernel 1: x fp32 -> bf16 ----------------
__global__ __launch_bounds__(256) void k_convert_x(const float* __restrict__ x,
                                                   unsigned short* __restrict__ xb) {
    int i = (blockIdx.x * 256 + threadIdx.x) * 4;
    f32x4 v = *reinterpret_cast<const f32x4*>(x + i);
    ushort4 o;
    o.x = f2bf(v[0]); o.y = f2bf(v[1]); o.z = f2bf(v[2]); o.w = f2bf(v[3]);
    *reinterpret_cast<ushort4*>(xb + i) = o;
}

// Shared GEMM body: block of 4 waves owns 64 weight rows; weights staged to LDS
// via global_load_lds (256B-contiguous per row per step) with XOR(row&7)<<4
// swizzle applied on the GLOBAL SOURCE (LDS dest linear) and on the ds_read.
// A (activations, bf16, L2/L3-resident) staged to padded LDS.
template <int LDK>  // row stride (elements) of both W and A in global memory
__device__ __forceinline__ void gemm_body(const unsigned short* __restrict__ ab,
                                          const float* __restrict__ w, int n0,
                                          int sbeg, int send, float acc_out[8][4],
                                          unsigned short* xs, float* wlds) {
    const int tid = threadIdx.x;
    const int wv = tid >> 6, lane = tid & 63;
    const int r16 = lane & 15, g4 = lane >> 4;

    f32x4 acc[8];
#pragma unroll
    for (int i = 0; i < 8; ++i) acc[i] = (f32x4)0.0f;

    // per-lane constants for the weight DMA (4 instrs, j=0..3)
    // instr j: rows [wv*16+j*4, +4), lane covers row +(lane>>4), 16B chunk (lane&15)
    const int wrow_b = wv * 16;

    for (int s = sbeg; s < send; ++s) {
        const int k0 = s * 64;
        __syncthreads();  // previous step's compute done before overwrite
        // ---- weight DMA: 16KB, 256B contiguous per row ----
#pragma unroll
        for (int j = 0; j < 4; ++j) {
            int row = wrow_b + j * 4 + g4;
            const float* src = w + (size_t)(n0 + row) * LDK + k0 + (((lane & 15) ^ (row & 7)) << 2);
            __builtin_amdgcn_global_load_lds((as1_u32*)src, (as3_u32*)&wlds[(wrow_b + j * 4) * 64],
                                             16, 0, 0);
        }
        // ---- A staging: 128 rows x 64 bf16 (pad to 72) ----
#pragma unroll
        for (int i = 0; i < 4; ++i) {
            int u = tid + i * 256, row = u >> 3, off = u & 7;
            *reinterpret_cast<uint4*>(&xs[row * 72 + off * 8]) =
                *reinterpret_cast<const uint4*>(ab + (size_t)row * LDK + k0 + off * 8);
        }
        __syncthreads();
        // ---- compute ----
        const char* wrow = (const char*)&wlds[(wv * 16 + r16) * 64];
        const unsigned swz = (unsigned)((r16 & 7) << 4);
#pragma unroll
        for (int kk = 0; kk < 64; kk += 32) {
            f32x4 b0 = *reinterpret_cast<const f32x4*>(wrow + ((unsigned)((kk + g4 * 8) * 4) ^ swz));
            f32x4 b1 = *reinterpret_cast<const f32x4*>(wrow + ((unsigned)((kk + g4 * 8 + 4) * 4) ^ swz));
            s16x8 bf = cvt8(b0, b1);
#pragma unroll
            for (int mt = 0; mt < 8; ++mt) {
                s16x8 af = *reinterpret_cast<const s16x8*>(&xs[(mt * 16 + r16) * 72 + kk + g4 * 8]);
                acc[mt] = __builtin_amdgcn_mfma_f32_16x16x32_bf16(af, bf, acc[mt], 0, 0, 0);
            }
        }
    }
#pragma unroll
    for (int mt = 0; mt < 8; ++mt)
#pragma unroll
        for (int r = 0; r < 4; ++r) acc_out[mt][r] = acc[mt][r];
}

// ---------------- kernel 2: gate & up GEMM ----------------
// grid.x = 172 * 2 * Sg ; block = 256
__global__ __launch_bounds__(256, 4) void k_gateup3(const unsigned short* __restrict__ xb,
                                                    const float* __restrict__ wg,
                                                    const float* __restrict__ wu,
                                                    float* __restrict__ pg,
                                                    float* __restrict__ pu, int Sg) {
    __shared__ __align__(16) unsigned short xs[MTOK * 72];  // 18432 B
    __shared__ __align__(16) float wlds[64 * 64];           // 16384 B
    const int gid = blockIdx.x;
    const int nt = gid % 172, rest = gid / 172;
    const int mat = rest & 1, kc = rest >> 1;
    const int n0 = nt * 64;
    const int nk = (HIDDEN / 64) / Sg;

    float acc[8][4];
    gemm_body<HIDDEN>(xb, mat ? wu : wg, n0, kc * nk, (kc + 1) * nk, acc, xs, wlds);

    const int lane = threadIdx.x & 63, wv = threadIdx.x >> 6;
    const int r16 = lane & 15, g4 = lane >> 4;
    float* p = (mat ? pu : pg) + (size_t)kc * (MTOK * INTER);
#pragma unroll
    for (int mt = 0; mt < 8; ++mt)
#pragma unroll
        for (int r = 0; r < 4; ++r) {
            int m = mt * 16 + g4 * 4 + r;
            p[(size_t)m * INTER + n0 + wv * 16 + r16] = acc[mt][r];
        }
}

// ---------------- kernel 3: combine partials + silu*up -> hb bf16 ----------------
__global__ __launch_bounds__(256) void k_combine(const float* __restrict__ pg,
                                                 const float* __restrict__ pu,
                                                 unsigned short* __restrict__ hb, int Sg) {
    size_t i = (size_t)(blockIdx.x * 256 + threadIdx.x) * 4;
    f32x4 g = (f32x4)0.0f, u = (f32x4)0.0f;
    for (int c = 0; c < Sg; ++c) {
        g += *reinterpret_cast<const f32x4*>(pg + (size_t)c * (MTOK * INTER) + i);
        u += *reinterpret_cast<const f32x4*>(pu + (size_t)c * (MTOK * INTER) + i);
    }
    ushort4 o;
    o.x = f2bf(g[0] / (1.0f + __expf(-g[0])) * u[0]);
    o.y = f2bf(g[1] / (1.0f + __expf(-g[1])) * u[1]);
    o.z = f2bf(g[2] / (1.0f + __expf(-g[2])) * u[2]);
    o.w = f2bf(g[3] / (1.0f + __expf(-g[3])) * u[3]);
    *reinterpret_cast<ushort4*>(hb + i) = o;
}

// ---------------- kernel 4: down GEMM ----------------
// grid.x = 64 * Sd ; block = 256. K-steps [0,172) split across Sd chunks.
__global__ __launch_bounds__(256, 4) void k_down3(const unsigned short* __restrict__ hb,
                                                  const float* __restrict__ wd,
                                                  float* __restrict__ pd, int Sd) {
    __shared__ __align__(16) unsigned short xs[MTOK * 72];
    __shared__ __align__(16) float wlds[64 * 64];
    const int gid = blockIdx.x;
    const int nt = gid % 64, kc = gid / 64;
    const int n0 = nt * 64;
    const int sbeg = (172 * kc) / Sd, send = (172 * (kc + 1)) / Sd;

    float acc[8][4];
    gemm_body<INTER>(hb, wd, n0, sbeg, send, acc, xs, wlds);

    const int lane = threadIdx.x & 63, wv = threadIdx.x >> 6;
    const int r16 = lane & 15, g4 = lane >> 4;
    float* p = pd + (size_t)kc * (MTOK * HIDDEN);
#pragma unroll
    for (int mt = 0; mt < 8; ++mt)
#pragma unroll
        for (int r = 0; r < 4; ++r) {
            int m = mt * 16 + g4 * 4 + r;
            p[(size_t)m * HIDDEN + n0 + wv * 16 + r16] = acc[mt][r];
        }
}

// ---------------- kernel 5: reduce Sd partials -> out ----------------
__global__ __launch_bounds__(256) void k_reduce(const float* __restrict__ pd,
                                                float* __restrict__ out, int Sd) {
    int i = (blockIdx.x * 256 + threadIdx.x) * 4;
    const int NT = MTOK * HIDDEN;
    f32x4 s = (f32x4)0.0f;
    for (int c = 0; c < Sd; ++c)
        s += *reinterpret_cast<const f32x4*>(pd + (size_t)c * NT + i);
    *reinterpret_cast<f32x4*>(out + i) = s;
}

extern "C" void kernel_launch(void* const* d_in, const int* in_sizes, int n_in,
                              void* d_out, int out_size, void* d_ws, size_t ws_size,
                              hipStream_t stream) {
    const float* x  = (const float*)d_in[0];
    const float* wg = (const float*)d_in[1];
    const float* wu = (const float*)d_in[2];
    const float* wd = (const float*)d_in[3];
    float* out = (float*)d_out;

    const size_t XB = 1048576;
    const size_t HB = 2818048;
    const size_t PGU = (size_t)MTOK * INTER * 4;   // per split per matrix
    const size_t PD  = (size_t)MTOK * HIDDEN * 4;  // per split
    const int cfg[5][2] = {{4, 16}, {4, 8}, {2, 8}, {2, 4}, {1, 2}};
    int Sg = 1, Sd = 2;
    for (int c = 0; c < 5; ++c) {
        size_t need = XB + HB + 2 * (size_t)cfg[c][0] * PGU + (size_t)cfg[c][1] * PD;
        if (need <= ws_size) { Sg = cfg[c][0]; Sd = cfg[c][1]; break; }
    }

    char* ws = (char*)d_ws;
    unsigned short* xb = (unsigned short*)ws;
    unsigned short* hb = (unsigned short*)(ws + XB);
    float* pg = (float*)(ws + XB + HB);
    float* pu = pg + (size_t)Sg * (MTOK * INTER);
    float* pd = pu + (size_t)Sg * (MTOK * INTER);

    k_convert_x<<<512, 256, 0, stream>>>(x, xb);
    k_gateup3<<<172 * 2 * Sg, 256, 0, stream>>>(xb, wg, wu, pg, pu, Sg);
    k_combine<<<1376, 256, 0, stream>>>(pg, pu, hb, Sg);
    k_down3<<<64 * Sd, 256, 0, stream>>>(hb, wd, pd, Sd);
    k_reduce<<<512, 256, 0, stream>>>(pd, out, Sd);
}